// Round 15
// baseline (175.618 us; speedup 1.0000x reference)
//
#include <hip/hip_runtime.h>
#include <hip/hip_bf16.h>

#define N_NODES 50000
#define E_EDGES 800000
#define NHEAD 4
#define DHEAD 32
#define DOUT 128   // NHEAD*DHEAD == D_IN
#define NEG_SLOPE 0.01f
#define EPS_F 1e-16f
#define DMAX 256
#define NB 196     // dst buckets of 256 nodes (dst>>8), 49999>>8 == 195
#define CAP 8192   // payload capacity per bucket (mean 4096, sigma 64)
#define XSP 136    // bf16 x-stage pitch (272 B/row)
#define NGB 782    // 782*64 == 50048 row-groups

typedef __attribute__((ext_vector_type(8))) short bf16x8;
typedef __attribute__((ext_vector_type(4))) float f32x4;

__device__ __forceinline__ float bf2f(unsigned short u) {
    return __uint_as_float((unsigned)u << 16);
}
__device__ __forceinline__ unsigned short f2bf(float f) {
    return __bfloat16_as_ushort(__float2bfloat16(f));   // RNE
}

// ---- edge index fetch, robust to int32 vs int64 storage ----
__device__ __forceinline__ void load_edge(const int* __restrict__ ei, int isI64,
                                          int e, int& src, int& dst) {
    if (isI64) { src = ei[2 * e]; dst = ei[2 * (E_EDGES + e)]; }
    else       { src = ei[e];     dst = ei[E_EDGES + e]; }
}

// ---- K0: weights -> MFMA-fragment-ordered bf16 (blocks 0..255); block 256:
// ---- int64-detect + bucketCnt zeroing.
__global__ __launch_bounds__(128) void k_prep(const float* __restrict__ Wp,
                                              const float* __restrict__ Ws,
                                              const int* __restrict__ ei,
                                              unsigned short* __restrict__ Wt,
                                              int* __restrict__ bucketCnt,
                                              int* __restrict__ flag) {
    int b = blockIdx.x;
    if (b < 256) {
        int c = b, k = threadIdx.x;   // col c of [Wp|Ws], row k
        float v = (c < DOUT) ? Wp[k * DOUT + c] : Ws[k * DOUT + (c - DOUT)];
        int nf = c >> 4, cl = c & 15;
        int ks = k >> 5, r = k & 31, lq = r >> 3, e = r & 7;
        Wt[(((nf * 4 + ks) << 6) + lq * 16 + cl) * 8 + e] = f2bf(v);
    } else {
        __shared__ int cnt;
        if (threadIdx.x == 0) cnt = 0;
        if (threadIdx.x < 128 && (int)threadIdx.x < NB) {
            bucketCnt[threadIdx.x] = 0;
            if (threadIdx.x + 128 < NB) bucketCnt[threadIdx.x + 128] = 0;
        }
        __syncthreads();
        int nz = 0;
        #pragma unroll
        for (int k2 = 0; k2 < 16; ++k2) {
            int pos = (threadIdx.x + k2 * 128) * 2 + 1;   // odd int32 slots
            if (ei[pos] != 0) nz = 1;
        }
        if (nz) atomicOr(&cnt, 1);
        __syncthreads();
        if (threadIdx.x == 0) *flag = (cnt == 0) ? 1 : 0;
    }
}

// ---- K1: FUSED [blocks 0..255: bucket partition][256..1819: split GEMM] ----
// (unchanged from R14)
__global__ __launch_bounds__(256) void k_gemm_part(const float* __restrict__ x,
                                                   const unsigned short* __restrict__ Wt,
                                                   const float* __restrict__ att,
                                                   const int* __restrict__ ei,
                                                   const int* __restrict__ flag,
                                                   int* __restrict__ bucketCnt,
                                                   unsigned* __restrict__ payload,
                                                   unsigned short* __restrict__ hb,
                                                   float* __restrict__ as_,
                                                   float* __restrict__ ad_,
                                                   float* __restrict__ out) {
    __shared__ __align__(16) char BUF[64 * XSP * 2];   // 17408 B, unioned
    const int tid = threadIdx.x;

    if (blockIdx.x < 256) {
        int* hist = (int*)BUF;
        int* curs = hist + NB;
        const int base = blockIdx.x * 3125;
        const int isI64 = *flag;

        for (int i = tid; i < NB; i += 256) hist[i] = 0;
        __syncthreads();
        for (int i = tid; i < 3125; i += 256) {
            int src, dst;
            load_edge(ei, isI64, base + i, src, dst);
            if ((unsigned)dst < N_NODES) atomicAdd(&hist[dst >> 8], 1);
        }
        __syncthreads();
        for (int i = tid; i < NB; i += 256)
            curs[i] = atomicAdd(&bucketCnt[i], hist[i]);
        __syncthreads();
        for (int i = tid; i < 3125; i += 256) {
            int src, dst;
            load_edge(ei, isI64, base + i, src, dst);
            if ((unsigned)src >= N_NODES || (unsigned)dst >= N_NODES) continue;
            int b = dst >> 8;
            int pos = atomicAdd(&curs[b], 1);
            if (pos < CAP)
                payload[((size_t)b << 13) + pos] = ((unsigned)(dst & 255) << 16) | (unsigned)src;
        }
        return;
    }

    unsigned short* XSB = (unsigned short*)BUF;   // [64][XSP] bf16
    const int gbp  = blockIdx.x - 256;            // 0..1563
    const int gb   = gbp >> 1;                    // row-group 0..781
    const int half = gbp & 1;                     // 0: h, 1: skip
    const int rw  = tid >> 6;
    const int l   = tid & 63;
    const int l15 = l & 15;
    const int lq  = l >> 4;
    const int rowbase = gb * 64 + rw * 16;

    {
        #pragma unroll
        for (int it = 0; it < 8; ++it) {
            int e = it * 1024 + tid * 4;          // element index
            int row = e >> 7, col = e & 127;
            int grow = gb * 64 + row;
            if (grow > N_NODES - 1) grow = N_NODES - 1;
            float4 v = *(const float4*)(x + (size_t)grow * DOUT + col);
            ushort4 pk = make_ushort4(f2bf(v.x), f2bf(v.y), f2bf(v.z), f2bf(v.w));
            *(ushort4*)(XSB + row * XSP + col) = pk;
        }
    }
    __syncthreads();

    bf16x8 xfr[4];
    const char* xrow = (const char*)XSB + (rw * 16 + l15) * (XSP * 2);
    #pragma unroll
    for (int ks = 0; ks < 4; ++ks)
        xfr[ks] = *(const bf16x8*)(xrow + ks * 64 + lq * 16);

    f32x4 acc[8];
    #pragma unroll
    for (int nf = 0; nf < 8; ++nf) acc[nf] = (f32x4)(0.0f);

    const int nfbase = half * 8;
    #pragma unroll
    for (int nf = 0; nf < 8; ++nf) {
        #pragma unroll
        for (int ks = 0; ks < 4; ++ks) {
            bf16x8 w = *(const bf16x8*)(Wt + (((((nfbase + nf) * 4 + ks) << 6) + l) << 3));
            acc[nf] = __builtin_amdgcn_mfma_f32_16x16x32_bf16(w, xfr[ks], acc[nf], 0, 0, 0);
        }
    }

    const int r = rowbase + l15;                  // this lane's node row
    if (half == 0) {
        float ps1[4] = {0.f, 0.f, 0.f, 0.f}, ps2[4] = {0.f, 0.f, 0.f, 0.f};
        #pragma unroll
        for (int nf = 0; nf < 8; ++nf) {
            int hd = nf >> 1;
            int jb = (nf & 1) * 16 + lq * 4;      // col within head
            float4 w1 = *(const float4*)(att + hd * 2 * DHEAD + jb);
            float4 w2 = *(const float4*)(att + hd * 2 * DHEAD + DHEAD + jb);
            f32x4 v = acc[nf];
            ps1[hd] += v[0] * w1.x + v[1] * w1.y + v[2] * w1.z + v[3] * w1.w;
            ps2[hd] += v[0] * w2.x + v[1] * w2.y + v[2] * w2.z + v[3] * w2.w;
            ushort4 pk = make_ushort4(f2bf(v[0]), f2bf(v[1]), f2bf(v[2]), f2bf(v[3]));
            *(ushort4*)(hb + (size_t)r * DOUT + nf * 16 + lq * 4) = pk;   // hb padded
        }
        #pragma unroll
        for (int hd = 0; hd < 4; ++hd) {
            ps1[hd] += __shfl_xor(ps1[hd], 16); ps1[hd] += __shfl_xor(ps1[hd], 32);
            ps2[hd] += __shfl_xor(ps2[hd], 16); ps2[hd] += __shfl_xor(ps2[hd], 32);
        }
        if (lq == 0) {
            #pragma unroll
            for (int hd = 0; hd < 4; ++hd) {      // as_/ad_ padded to 50048
                as_[(size_t)r * 4 + hd] = ps1[hd];
                ad_[(size_t)r * 4 + hd] = ps2[hd];
            }
        }
    } else {
        if (r < N_NODES) {
            #pragma unroll
            for (int nf = 0; nf < 8; ++nf) {
                f32x4 v = acc[nf];
                *(float4*)(out + (size_t)r * DOUT + nf * 16 + lq * 4) =
                    make_float4(v[0], v[1], v[2], v[3]);
            }
        }
    }
}

// ---- K2b: per-bucket CSR build (unchanged) ----
__global__ __launch_bounds__(256) void k_csr(const int* __restrict__ bucketCnt,
                                             const unsigned* __restrict__ payload,
                                             int* __restrict__ deg,
                                             int* __restrict__ ofs,
                                             int* __restrict__ srcs) {
    __shared__ int h[256];
    __shared__ int cur[256];
    __shared__ int sc[256];
    const int b = blockIdx.x;
    const int t = threadIdx.x;
    int cnt = bucketCnt[b];
    if (cnt > CAP) cnt = CAP;
    const unsigned* __restrict__ pl = payload + ((size_t)b << 13);

    h[t] = 0;
    __syncthreads();
    for (int i = t; i < cnt; i += 256) atomicAdd(&h[pl[i] >> 16], 1);
    __syncthreads();
    int v = h[t];
    sc[t] = v;
    __syncthreads();
    #pragma unroll
    for (int off = 1; off < 256; off <<= 1) {
        int u = (t >= off) ? sc[t - off] : 0;
        __syncthreads();
        sc[t] += u;
        __syncthreads();
    }
    int ex = sc[t] - v;              // exclusive local prefix
    cur[t] = ex;
    int n = (b << 8) + t;
    if (n < N_NODES) { deg[n] = v; ofs[n] = (b << 13) + ex; }
    __syncthreads();
    for (int i = t; i < cnt; i += 256) {
        unsigned p = pl[i];
        int pos = atomicAdd(&cur[p >> 16], 1);
        srcs[((size_t)b << 13) + pos] = (int)(p & 0xFFFFu);
    }
}

// ---- K3: head-sliced XCD-local gather v7 ----
// Grid 12500 x 4: block (bq = blockIdx>>2, hd = blockIdx&3) = 4 nodes x head hd.
// Wave wid owns node bq*4+wid. Gathers touch ONLY head hd's 64B line of each hb
// row: per-XCD working set 50000x64B = 3.2 MB fits the 4 MB XCD L2 under
// round-robin blockIdx->XCD. Per gather instr: 4 edge-groups x 16 lanes = 4 rows'
// single lines. Softmax (el/max/exp/den) computed for head hd only -> chip-wide
// softmax work unchanged vs R14.
__global__ __launch_bounds__(256) void k_gat(const int* __restrict__ ofs,
                                             const int* __restrict__ deg,
                                             const int* __restrict__ srcs,
                                             const float* __restrict__ as_,
                                             const float* __restrict__ ad_,
                                             const unsigned short* __restrict__ hb,
                                             float* __restrict__ out) {
    __shared__ int   SRC[4][DMAX];   // 4 KB
    __shared__ float EL[4][DMAX];    // 4 KB

    const int hd  = blockIdx.x & 3;
    const int bq  = blockIdx.x >> 2;
    const int wid = threadIdx.x >> 6;
    const int l   = threadIdx.x & 63;
    const int g   = l >> 4;              // edge-group within wave
    const int c   = l & 15;              // uint column within head slice
    const int n   = bq * 4 + wid;        // 12500*4 == 50000 exactly
    const int o = ofs[n];
    const int d = deg[n];
    const unsigned* __restrict__ hbu = (const unsigned*)hb;
    int*   SRCw = SRC[wid];
    float* ELw  = EL[wid];

    int fast = __syncthreads_and(d <= DMAX);   // block-uniform branch

    if (fast) {
        // phase A: stage srcs + this head's leaky-relu logits
        const float adv = ad_[(size_t)n * 4 + hd];
        for (int i = l; i < d; i += 64) {
            int s = srcs[o + i];
            SRCw[i] = s;
            float e = as_[(size_t)s * 4 + hd] + adv;
            ELw[i] = (e > 0.0f) ? e : NEG_SLOPE * e;
        }
        __syncthreads();
        // phase B: wave-wide max, exp in place, den, normalize (alpha = p/den)
        float m = -3.4e38f;
        for (int i = l; i < d; i += 64) m = fmaxf(m, ELw[i]);
        #pragma unroll
        for (int off = 32; off; off >>= 1) m = fmaxf(m, __shfl_xor(m, off));
        float den = 0.0f;
        for (int i = l; i < d; i += 64) {
            float p = __expf(ELw[i] - m);
            ELw[i] = p;
            den += p;
        }
        #pragma unroll
        for (int off = 32; off; off >>= 1) den += __shfl_xor(den, off);
        float inv = 1.0f / (den + EPS_F);
        for (int i = l; i < d; i += 64) ELw[i] *= inv;
        __syncthreads();
        // phase C: 4 edges per iteration, one 64B line per edge-group
        float num0 = 0.0f, num1 = 0.0f;
        for (int i = 0; i < d; i += 4) {
            int e = i + g;
            if (e < d) {
                float a = ELw[e];
                unsigned u = hbu[(size_t)SRCw[e] * (DOUT / 2) + hd * 16 + c];
                num0 = fmaf(a, bf2f((unsigned short)(u & 0xffff)), num0);
                num1 = fmaf(a, bf2f((unsigned short)(u >> 16)), num1);
            }
        }
        num0 += __shfl_xor(num0, 16); num0 += __shfl_xor(num0, 32);
        num1 += __shfl_xor(num1, 16); num1 += __shfl_xor(num1, 32);
        if (g == 0) {
            float2* op = (float2*)(out + (size_t)n * DOUT + hd * DHEAD + 2 * c);
            float2 sk = *op;
            *op = make_float2(num0 + sk.x, num1 + sk.y);
        }
    } else {
        // fallback (degree > DMAX, statistically never for this graph):
        // redundant two-pass per wave, alpha recomputed in gather loop.
        const float adv = ad_[(size_t)n * 4 + hd];
        float m = -3.4e38f;
        for (int i = 0; i < d; ++i) {
            float e = as_[(size_t)srcs[o + i] * 4 + hd] + adv;
            e = (e > 0.0f) ? e : NEG_SLOPE * e;
            m = fmaxf(m, e);
        }
        float den = 0.0f;
        for (int i = 0; i < d; ++i) {
            float e = as_[(size_t)srcs[o + i] * 4 + hd] + adv;
            e = (e > 0.0f) ? e : NEG_SLOPE * e;
            den += __expf(e - m);
        }
        float inv = 1.0f / (den + EPS_F);
        float num0 = 0.0f, num1 = 0.0f;
        for (int i = 0; i < d; i += 4) {
            int e = i + g;
            if (e < d) {
                int s = srcs[o + e];
                float el = as_[(size_t)s * 4 + hd] + adv;
                el = (el > 0.0f) ? el : NEG_SLOPE * el;
                float a = __expf(el - m) * inv;
                unsigned u = hbu[(size_t)s * (DOUT / 2) + hd * 16 + c];
                num0 = fmaf(a, bf2f((unsigned short)(u & 0xffff)), num0);
                num1 = fmaf(a, bf2f((unsigned short)(u >> 16)), num1);
            }
        }
        num0 += __shfl_xor(num0, 16); num0 += __shfl_xor(num0, 32);
        num1 += __shfl_xor(num1, 16); num1 += __shfl_xor(num1, 32);
        if (g == 0) {
            float2* op = (float2*)(out + (size_t)n * DOUT + hd * DHEAD + 2 * c);
            float2 sk = *op;
            *op = make_float2(num0 + sk.x, num1 + sk.y);
        }
    }
}

extern "C" void kernel_launch(void* const* d_in, const int* in_sizes, int n_in,
                              void* d_out, int out_size, void* d_ws, size_t ws_size,
                              hipStream_t stream) {
    const float* x   = (const float*)d_in[0];
    const float* Wp  = (const float*)d_in[1];
    const float* att = (const float*)d_in[2];
    const float* Ws  = (const float*)d_in[3];
    const int*   ei  = (const int*)d_in[4];
    float* out = (float*)d_out;

    char* ws = (char*)d_ws;
    unsigned short* hb        = (unsigned short*)(ws);              // 12,812,288 B (50048 rows)
    unsigned short* Wt        = (unsigned short*)(ws + 12812288);   // 65,536 B
    float*          as_       = (float*)(ws + 12877824);            // 800,768 B
    float*          ad_       = (float*)(ws + 13678592);            // 800,768 B
    int*            deg       = (int*)(ws + 14479360);              // 200,704 B
    int*            ofs       = (int*)(ws + 14680064);              // 200,704 B
    unsigned*       payload   = (unsigned*)(ws + 14880768);         // 6,422,528 B
    int*            srcs      = (int*)(ws + 21303296);              // 6,422,528 B
    int*            bucketCnt = (int*)(ws + 27725824);              // 1,024 B
    int*            flag      = (int*)(ws + 27726848);

    k_prep<<<257, 128, 0, stream>>>(Wp, Ws, ei, Wt, bucketCnt, flag);
    k_gemm_part<<<256 + 2 * NGB, 256, 0, stream>>>(
        x, Wt, att, ei, flag, bucketCnt, payload, hb, as_, ad_, out);
    k_csr<<<NB, 256, 0, stream>>>(bucketCnt, payload, deg, ofs, srcs);
    k_gat<<<(N_NODES / 4) * 4, 256, 0, stream>>>(ofs, deg, srcs, as_, ad_, hb, out);
}

// Round 16
// 99.821 us; speedup vs baseline: 1.7593x; 1.7593x over previous
//
#include <hip/hip_runtime.h>
#include <hip/hip_bf16.h>

#define N_NODES 50000
#define E_EDGES 800000
#define NHEAD 4
#define DHEAD 32
#define DOUT 128   // NHEAD*DHEAD == D_IN
#define NEG_SLOPE 0.01f
#define EPS_F 1e-16f
#define DMAX 256
#define ELP 264    // EL head pitch (words); 264%32==8 -> heads hit distinct banks
#define NB 196     // dst buckets of 256 nodes (dst>>8), 49999>>8 == 195
#define CAP 8192   // payload capacity per bucket (mean 4096, sigma 64)
#define XSP 136    // bf16 x-stage pitch (272 B/row)
#define NGB 782    // 782*64 == 50048 row-groups

typedef __attribute__((ext_vector_type(8))) short bf16x8;
typedef __attribute__((ext_vector_type(4))) float f32x4;

__device__ __forceinline__ float bf2f(unsigned short u) {
    return __uint_as_float((unsigned)u << 16);
}
__device__ __forceinline__ unsigned short f2bf(float f) {
    return __bfloat16_as_ushort(__float2bfloat16(f));   // RNE
}

// ---- edge index fetch, robust to int32 vs int64 storage ----
__device__ __forceinline__ void load_edge(const int* __restrict__ ei, int isI64,
                                          int e, int& src, int& dst) {
    if (isI64) { src = ei[2 * e]; dst = ei[2 * (E_EDGES + e)]; }
    else       { src = ei[e];     dst = ei[E_EDGES + e]; }
}

// ---- K0: weights -> MFMA-fragment-ordered bf16 (blocks 0..255); block 256:
// ---- int64-detect + bucketCnt zeroing (memset dispatch folded in).
__global__ __launch_bounds__(128) void k_prep(const float* __restrict__ Wp,
                                              const float* __restrict__ Ws,
                                              const int* __restrict__ ei,
                                              unsigned short* __restrict__ Wt,
                                              int* __restrict__ bucketCnt,
                                              int* __restrict__ flag) {
    int b = blockIdx.x;
    if (b < 256) {
        int c = b, k = threadIdx.x;   // col c of [Wp|Ws], row k
        float v = (c < DOUT) ? Wp[k * DOUT + c] : Ws[k * DOUT + (c - DOUT)];
        int nf = c >> 4, cl = c & 15;
        int ks = k >> 5, r = k & 31, lq = r >> 3, e = r & 7;
        Wt[(((nf * 4 + ks) << 6) + lq * 16 + cl) * 8 + e] = f2bf(v);
    } else {
        __shared__ int cnt;
        if (threadIdx.x == 0) cnt = 0;
        if (threadIdx.x < 128 && (int)threadIdx.x < NB) {
            bucketCnt[threadIdx.x] = 0;
            if (threadIdx.x + 128 < NB) bucketCnt[threadIdx.x + 128] = 0;
        }
        __syncthreads();
        int nz = 0;
        #pragma unroll
        for (int k2 = 0; k2 < 16; ++k2) {
            int pos = (threadIdx.x + k2 * 128) * 2 + 1;   // odd int32 slots
            if (ei[pos] != 0) nz = 1;
        }
        if (nz) atomicOr(&cnt, 1);
        __syncthreads();
        if (threadIdx.x == 0) *flag = (cnt == 0) ? 1 : 0;
    }
}

// ---- K1: FUSED [blocks 0..255: bucket partition][256..1819: split GEMM] ----
// GEMM pair (gb, half): same 64-row x-stage; half 0 -> nf 0-7 (hb + attdot),
// half 1 -> nf 8-15 (skip->out). Per wave: 32 MFMA, 32 KB Wt slice (L1-fits),
// acc = 32 AGPR. D^T = mfma(A=W-frag, B=x-frag); lane holds 4 consecutive
// output cols of node row (lane&15).
__global__ __launch_bounds__(256) void k_gemm_part(const float* __restrict__ x,
                                                   const unsigned short* __restrict__ Wt,
                                                   const float* __restrict__ att,
                                                   const int* __restrict__ ei,
                                                   const int* __restrict__ flag,
                                                   int* __restrict__ bucketCnt,
                                                   unsigned* __restrict__ payload,
                                                   unsigned short* __restrict__ hb,
                                                   float* __restrict__ as_,
                                                   float* __restrict__ ad_,
                                                   float* __restrict__ out) {
    __shared__ __align__(16) char BUF[64 * XSP * 2];   // 17408 B, unioned
    const int tid = threadIdx.x;

    if (blockIdx.x < 256) {
        // ================= bucket partition =================
        int* hist = (int*)BUF;
        int* curs = hist + NB;
        const int base = blockIdx.x * 3125;
        const int isI64 = *flag;

        for (int i = tid; i < NB; i += 256) hist[i] = 0;
        __syncthreads();
        for (int i = tid; i < 3125; i += 256) {
            int src, dst;
            load_edge(ei, isI64, base + i, src, dst);
            if ((unsigned)dst < N_NODES) atomicAdd(&hist[dst >> 8], 1);
        }
        __syncthreads();
        for (int i = tid; i < NB; i += 256)
            curs[i] = atomicAdd(&bucketCnt[i], hist[i]);
        __syncthreads();
        for (int i = tid; i < 3125; i += 256) {
            int src, dst;
            load_edge(ei, isI64, base + i, src, dst);
            if ((unsigned)src >= N_NODES || (unsigned)dst >= N_NODES) continue;
            int b = dst >> 8;
            int pos = atomicAdd(&curs[b], 1);
            if (pos < CAP)
                payload[((size_t)b << 13) + pos] = ((unsigned)(dst & 255) << 16) | (unsigned)src;
        }
        return;
    }

    // ============================ GEMM ============================
    unsigned short* XSB = (unsigned short*)BUF;   // [64][XSP] bf16
    const int gbp  = blockIdx.x - 256;            // 0..1563
    const int gb   = gbp >> 1;                    // row-group 0..781
    const int half = gbp & 1;                     // 0: h, 1: skip
    const int rw  = tid >> 6;
    const int l   = tid & 63;
    const int l15 = l & 15;
    const int lq  = l >> 4;
    const int rowbase = gb * 64 + rw * 16;

    // stage x[64][128] -> bf16 LDS (coalesced float4 reads, 8B writes)
    {
        #pragma unroll
        for (int it = 0; it < 8; ++it) {
            int e = it * 1024 + tid * 4;          // element index
            int row = e >> 7, col = e & 127;
            int grow = gb * 64 + row;
            if (grow > N_NODES - 1) grow = N_NODES - 1;
            float4 v = *(const float4*)(x + (size_t)grow * DOUT + col);
            ushort4 pk = make_ushort4(f2bf(v.x), f2bf(v.y), f2bf(v.z), f2bf(v.w));
            *(ushort4*)(XSB + row * XSP + col) = pk;
        }
    }
    __syncthreads();

    // x fragments (B-operand): one ds_read_b128 per ks
    bf16x8 xfr[4];
    const char* xrow = (const char*)XSB + (rw * 16 + l15) * (XSP * 2);
    #pragma unroll
    for (int ks = 0; ks < 4; ++ks)
        xfr[ks] = *(const bf16x8*)(xrow + ks * 64 + lq * 16);

    f32x4 acc[8];
    #pragma unroll
    for (int nf = 0; nf < 8; ++nf) acc[nf] = (f32x4)(0.0f);

    const int nfbase = half * 8;
    #pragma unroll
    for (int nf = 0; nf < 8; ++nf) {
        #pragma unroll
        for (int ks = 0; ks < 4; ++ks) {
            bf16x8 w = *(const bf16x8*)(Wt + (((((nfbase + nf) * 4 + ks) << 6) + l) << 3));
            acc[nf] = __builtin_amdgcn_mfma_f32_16x16x32_bf16(w, xfr[ks], acc[nf], 0, 0, 0);
        }
    }

    const int r = rowbase + l15;                  // this lane's node row
    if (half == 0) {
        // h half: hb 8B stores + in-register attdot partials
        float ps1[4] = {0.f, 0.f, 0.f, 0.f}, ps2[4] = {0.f, 0.f, 0.f, 0.f};
        #pragma unroll
        for (int nf = 0; nf < 8; ++nf) {
            int hd = nf >> 1;
            int jb = (nf & 1) * 16 + lq * 4;      // col within head
            float4 w1 = *(const float4*)(att + hd * 2 * DHEAD + jb);
            float4 w2 = *(const float4*)(att + hd * 2 * DHEAD + DHEAD + jb);
            f32x4 v = acc[nf];
            ps1[hd] += v[0] * w1.x + v[1] * w1.y + v[2] * w1.z + v[3] * w1.w;
            ps2[hd] += v[0] * w2.x + v[1] * w2.y + v[2] * w2.z + v[3] * w2.w;
            ushort4 pk = make_ushort4(f2bf(v[0]), f2bf(v[1]), f2bf(v[2]), f2bf(v[3]));
            *(ushort4*)(hb + (size_t)r * DOUT + nf * 16 + lq * 4) = pk;   // hb padded
        }
        #pragma unroll
        for (int hd = 0; hd < 4; ++hd) {
            ps1[hd] += __shfl_xor(ps1[hd], 16); ps1[hd] += __shfl_xor(ps1[hd], 32);
            ps2[hd] += __shfl_xor(ps2[hd], 16); ps2[hd] += __shfl_xor(ps2[hd], 32);
        }
        if (lq == 0) {
            #pragma unroll
            for (int hd = 0; hd < 4; ++hd) {      // as_/ad_ padded to 50048
                as_[(size_t)r * 4 + hd] = ps1[hd];
                ad_[(size_t)r * 4 + hd] = ps2[hd];
            }
        }
    } else {
        // skip half: direct guarded float4 stores
        if (r < N_NODES) {
            #pragma unroll
            for (int nf = 0; nf < 8; ++nf) {
                f32x4 v = acc[nf];
                *(float4*)(out + (size_t)r * DOUT + nf * 16 + lq * 4) =
                    make_float4(v[0], v[1], v[2], v[3]);
            }
        }
    }
}

// ---- K2b: per-bucket CSR build: deg/ofs (bucket-based) + srcs scatter ----
__global__ __launch_bounds__(256) void k_csr(const int* __restrict__ bucketCnt,
                                             const unsigned* __restrict__ payload,
                                             int* __restrict__ deg,
                                             int* __restrict__ ofs,
                                             int* __restrict__ srcs) {
    __shared__ int h[256];
    __shared__ int cur[256];
    __shared__ int sc[256];
    const int b = blockIdx.x;
    const int t = threadIdx.x;
    int cnt = bucketCnt[b];
    if (cnt > CAP) cnt = CAP;
    const unsigned* __restrict__ pl = payload + ((size_t)b << 13);

    h[t] = 0;
    __syncthreads();
    for (int i = t; i < cnt; i += 256) atomicAdd(&h[pl[i] >> 16], 1);
    __syncthreads();
    int v = h[t];
    sc[t] = v;
    __syncthreads();
    #pragma unroll
    for (int off = 1; off < 256; off <<= 1) {
        int u = (t >= off) ? sc[t - off] : 0;
        __syncthreads();
        sc[t] += u;
        __syncthreads();
    }
    int ex = sc[t] - v;              // exclusive local prefix
    cur[t] = ex;
    int n = (b << 8) + t;
    if (n < N_NODES) { deg[n] = v; ofs[n] = (b << 13) + ex; }
    __syncthreads();
    for (int i = t; i < cnt; i += 256) {
        unsigned p = pl[i];
        int pos = atomicAdd(&cur[p >> 16], 1);
        srcs[((size_t)b << 13) + pos] = (int)(p & 0xFFFFu);
    }
}

// ---- K3: per-node gather (R12 structure, pinned at its gather floor ~47us;
// ---- R10 fewer-instr, R11 2-wave, R15 head-sliced variants all regressed) ----
__global__ __launch_bounds__(128) void k_gat(const int* __restrict__ ofs,
                                             const int* __restrict__ deg,
                                             const int* __restrict__ srcs,
                                             const float* __restrict__ as_,
                                             const float* __restrict__ ad_,
                                             const unsigned short* __restrict__ hb,
                                             float* __restrict__ out) {
    __shared__ float EL[2][NHEAD * ELP];   // 2 x 4.2 KB
    __shared__ int   SRC[2][DMAX];         // 2 x 1 KB

    const int sub = threadIdx.x >> 6;      // node slot in block
    const int k   = threadIdx.x & 63;
    const int hd  = k >> 4;
    const int l16 = k & 15;
    const int n = blockIdx.x * 2 + sub;    // 25000*2 == 50000 exactly
    const int o = ofs[n];
    const int d = deg[n];
    const unsigned* __restrict__ hbu = (const unsigned*)hb;
    float* ELn = EL[sub];
    int*   SRCn = SRC[sub];

    int fast = __syncthreads_and(d <= DMAX);   // block-uniform branch

    if (fast) {
        const float4 adv4 = *(const float4*)(ad_ + (size_t)n * 4);
        for (int e = k; e < d; e += 64) {
            int s = srcs[o + e];
            SRCn[e] = s;
            float4 a4 = *(const float4*)(as_ + (size_t)s * 4);
            float e0 = a4.x + adv4.x, e1 = a4.y + adv4.y;
            float e2 = a4.z + adv4.z, e3 = a4.w + adv4.w;
            ELn[0 * ELP + e] = (e0 > 0.0f) ? e0 : NEG_SLOPE * e0;
            ELn[1 * ELP + e] = (e1 > 0.0f) ? e1 : NEG_SLOPE * e1;
            ELn[2 * ELP + e] = (e2 > 0.0f) ? e2 : NEG_SLOPE * e2;
            ELn[3 * ELP + e] = (e3 > 0.0f) ? e3 : NEG_SLOPE * e3;
        }
        __syncthreads();
        float m = -3.4e38f;
        for (int i = l16; i < d; i += 16) m = fmaxf(m, ELn[hd * ELP + i]);
        #pragma unroll
        for (int off = 8; off; off >>= 1) m = fmaxf(m, __shfl_xor(m, off));
        float den = 0.0f;
        for (int i = l16; i < d; i += 16) {
            float p = __expf(ELn[hd * ELP + i] - m);
            ELn[hd * ELP + i] = p;
            den += p;
        }
        #pragma unroll
        for (int off = 8; off; off >>= 1) den += __shfl_xor(den, off);
        __syncthreads();
        float num0 = 0.0f, num1 = 0.0f;
        int i = 0;
        for (; i + 4 <= d; i += 4) {
            int s0 = SRCn[i], s1 = SRCn[i + 1], s2 = SRCn[i + 2], s3 = SRCn[i + 3];
            unsigned u0 = hbu[(size_t)s0 * (DOUT / 2) + k];
            unsigned u1 = hbu[(size_t)s1 * (DOUT / 2) + k];
            unsigned u2 = hbu[(size_t)s2 * (DOUT / 2) + k];
            unsigned u3 = hbu[(size_t)s3 * (DOUT / 2) + k];
            float p0 = ELn[hd * ELP + i];
            float p1 = ELn[hd * ELP + i + 1];
            float p2 = ELn[hd * ELP + i + 2];
            float p3 = ELn[hd * ELP + i + 3];
            num0 = fmaf(p0, bf2f((unsigned short)(u0 & 0xffff)), num0);
            num1 = fmaf(p0, bf2f((unsigned short)(u0 >> 16)), num1);
            num0 = fmaf(p1, bf2f((unsigned short)(u1 & 0xffff)), num0);
            num1 = fmaf(p1, bf2f((unsigned short)(u1 >> 16)), num1);
            num0 = fmaf(p2, bf2f((unsigned short)(u2 & 0xffff)), num0);
            num1 = fmaf(p2, bf2f((unsigned short)(u2 >> 16)), num1);
            num0 = fmaf(p3, bf2f((unsigned short)(u3 & 0xffff)), num0);
            num1 = fmaf(p3, bf2f((unsigned short)(u3 >> 16)), num1);
        }
        for (; i < d; ++i) {
            float p = ELn[hd * ELP + i];
            int s = SRCn[i];
            unsigned u = hbu[(size_t)s * (DOUT / 2) + k];
            num0 = fmaf(p, bf2f((unsigned short)(u & 0xffff)), num0);
            num1 = fmaf(p, bf2f((unsigned short)(u >> 16)), num1);
        }
        float inv = 1.0f / (den + EPS_F);
        float2* op = (float2*)(out + (size_t)n * DOUT + 2 * k);
        float2 sk = *op;
        *op = make_float2(num0 * inv + sk.x, num1 * inv + sk.y);
    } else {
        const float adv = ad_[(size_t)n * 4 + hd];
        float m = -3.4e38f;
        for (int i = 0; i < d; ++i) {
            float el = as_[(size_t)srcs[o + i] * 4 + hd] + adv;
            el = (el > 0.0f) ? el : NEG_SLOPE * el;
            m = fmaxf(m, el);
        }
        float den = 0.0f, num0 = 0.0f, num1 = 0.0f;
        for (int i = 0; i < d; ++i) {
            int s = srcs[o + i];
            float el = as_[(size_t)s * 4 + hd] + adv;
            el = (el > 0.0f) ? el : NEG_SLOPE * el;
            float p = __expf(el - m);
            den += p;
            unsigned u = hbu[(size_t)s * (DOUT / 2) + k];
            num0 = fmaf(p, bf2f((unsigned short)(u & 0xffff)), num0);
            num1 = fmaf(p, bf2f((unsigned short)(u >> 16)), num1);
        }
        float inv = 1.0f / (den + EPS_F);
        float2* op = (float2*)(out + (size_t)n * DOUT + 2 * k);
        float2 sk = *op;
        *op = make_float2(num0 * inv + sk.x, num1 * inv + sk.y);
    }
}

extern "C" void kernel_launch(void* const* d_in, const int* in_sizes, int n_in,
                              void* d_out, int out_size, void* d_ws, size_t ws_size,
                              hipStream_t stream) {
    const float* x   = (const float*)d_in[0];
    const float* Wp  = (const float*)d_in[1];
    const float* att = (const float*)d_in[2];
    const float* Ws  = (const float*)d_in[3];
    const int*   ei  = (const int*)d_in[4];
    float* out = (float*)d_out;

    char* ws = (char*)d_ws;
    unsigned short* hb        = (unsigned short*)(ws);              // 12,812,288 B (50048 rows)
    unsigned short* Wt        = (unsigned short*)(ws + 12812288);   // 65,536 B
    float*          as_       = (float*)(ws + 12877824);            // 800,768 B
    float*          ad_       = (float*)(ws + 13678592);            // 800,768 B
    int*            deg       = (int*)(ws + 14479360);              // 200,704 B
    int*            ofs       = (int*)(ws + 14680064);              // 200,704 B
    unsigned*       payload   = (unsigned*)(ws + 14880768);         // 6,422,528 B
    int*            srcs      = (int*)(ws + 21303296);              // 6,422,528 B
    int*            bucketCnt = (int*)(ws + 27725824);              // 1,024 B
    int*            flag      = (int*)(ws + 27726848);

    k_prep<<<257, 128, 0, stream>>>(Wp, Ws, ei, Wt, bucketCnt, flag);
    k_gemm_part<<<256 + 2 * NGB, 256, 0, stream>>>(
        x, Wt, att, ei, flag, bucketCnt, payload, hb, as_, ad_, out);
    k_csr<<<NB, 256, 0, stream>>>(bucketCnt, payload, deg, ofs, srcs);
    k_gat<<<N_NODES / 2, 128, 0, stream>>>(ofs, deg, srcs, as_, ad_, hb, out);
}